// Round 3
// baseline (42.744 us; speedup 1.0000x reference)
//
#include <hip/hip_runtime.h>
#include <hip/hip_bf16.h>
#include <math.h>

#define Tt 50
#define Dd 64
#define Bb 4096
#define Ss 64
#define ROWP 68  // padded LDS row (ushorts)

// d_ws layout (bytes):
#define WS_SAMP 0        // bf16 sampT [64][64]   (8192 B)
#define WS_POS 8192      // float pos_score[64]   (256 B)
#define WS_SLOTS 8448    // 32 x u64, stride 64 B (2048 B)
#define WS_TICKET 10496  // u32 ticket

__device__ __forceinline__ float wsum(float v) {
#pragma unroll
  for (int m = 32; m >= 1; m >>= 1) v += __shfl_xor(v, m, 64);
  return v;
}
__device__ __forceinline__ float wmax(float v) {
#pragma unroll
  for (int m = 32; m >= 1; m >>= 1) v = fmaxf(v, __shfl_xor(v, m, 64));
  return v;
}
__device__ __forceinline__ float bf2f(unsigned short u) {
  return __uint_as_float(((unsigned)u) << 16);
}
__device__ __forceinline__ unsigned short f2bf(float f) {
  __hip_bfloat16 h = __float2bfloat16(f);  // RNE
  return __builtin_bit_cast(unsigned short, h);
}
// log(q), cancellation-free: log(id+2)-log(id+1) == log1p(1/(id+1))
__device__ __forceinline__ float logq_f(int id) {
  float idf = (float)id;
  float r = log1pf(1.0f / (idf + 1.0f));
  return logf(r * (1.0f / 12.2060776f));  // ln(200001)
}

__global__ __launch_bounds__(256) void pre_kernel(
    const float* __restrict__ item_table,
    const float* __restrict__ pos_table,
    const float* __restrict__ att_W,
    const int* __restrict__ sampled_ids,
    unsigned char* ws) {
  const int tid = threadIdx.x;
  if (blockIdx.x < 4) {
    // sampled table -> bf16, rows blockIdx*16 .. +15
    unsigned short* samp = (unsigned short*)(ws + WS_SAMP);
    int s = blockIdx.x * 16 + (tid >> 4);
    int d0 = (tid & 15) << 2;
    float4 v = *(const float4*)&item_table[(size_t)sampled_ids[s] * Dd + d0];
    ushort4 o;
    o.x = f2bf(v.x); o.y = f2bf(v.y); o.z = f2bf(v.z); o.w = f2bf(v.w);
    *(ushort4*)&samp[s * Dd + d0] = o;
  } else {
    float* poss = (float*)(ws + WS_POS);
    unsigned long long* slots = (unsigned long long*)(ws + WS_SLOTS);
    const int lane = tid & 63, w = tid >> 6;
    float wp = att_W[Dd + lane];
#pragma unroll
    for (int i = 0; i < 13; ++i) {
      int p = w * 13 + i;
      if (p < Tt) {
        float s = wsum(pos_table[p * Dd + lane] * wp);
        if (lane == 0) poss[p] = s;
      }
    }
    if (tid < 32) slots[tid * 8] = 0ull;
    if (tid == 32) *(unsigned int*)(ws + WS_TICKET) = 0u;
  }
}

__global__ __launch_bounds__(256) void u2i_kernel(
    const float* __restrict__ item_table,
    const float* __restrict__ att_W,
    const float* __restrict__ att_b,
    const float* __restrict__ prelu_alpha,
    const float* __restrict__ zero_bias,
    const int* __restrict__ items_id,
    const int* __restrict__ position_id,
    const int* __restrict__ target_id,
    const int* __restrict__ keys_length,
    const int* __restrict__ sampled_ids,
    unsigned char* ws,
    float* __restrict__ out_vec)  // [0..4095]=output, [4096]=loss
{
  __shared__ unsigned short itemsB[4][Tt][ROWP];  // 27200 B
  __shared__ float wv[4][Dd];
  __shared__ float ut1_lds[4][Dd];
  __shared__ long long red[4];

  const int tid = threadIdx.x;
  const int lane = tid & 63;
  const int w = tid >> 6;
  const int b = (blockIdx.x << 2) | w;

  int idreg = 0, pidreg = 0;
  if (lane < Tt) {
    idreg = items_id[b * Tt + lane];
    pidreg = position_id[b * Tt + lane];
  }
  const int kl = keys_length[b];

  // ---- stage this wave's 50 item rows -> LDS bf16 (wave-private) ----
#pragma unroll
  for (int t = 0; t < Tt; ++t) {
    int iid = __shfl(idreg, t, 64);
    float iv = item_table[(size_t)iid * Dd + lane];
    itemsB[w][t][lane] = f2bf(iv);
  }

  // ---- phase 2: lane = t -> score, softmax (no barrier needed: wave-private)
  const int trow = (lane < Tt) ? lane : (Tt - 1);
  const ushort4* rowp = (const ushort4*)&itemsB[w][trow][0];
  float a0 = 0, a1 = 0, a2 = 0, a3 = 0;
#pragma unroll
  for (int q = 0; q < 16; ++q) {
    ushort4 u = rowp[q];
    a0 += bf2f(u.x) * att_W[4 * q + 0];  // uniform -> scalar loads
    a1 += bf2f(u.y) * att_W[4 * q + 1];
    a2 += bf2f(u.z) * att_W[4 * q + 2];
    a3 += bf2f(u.w) * att_W[4 * q + 3];
  }
  float psc = ((const float*)(ws + WS_POS))[pidreg];
  float sc = tanhf((a0 + a1) + (a2 + a3) + psc + att_b[0]);
  float scv = (lane < kl) ? sc : -INFINITY;
  float m = wmax(scv);
  float e = (lane < kl) ? expf(sc - m) : 0.0f;
  float denom = wsum(e);
  wv[w][lane] = e / denom;
  unsigned long long mask = __ballot(lane < Tt - 1 && idreg != 0);

  // ---- phase 3: lane = (c = t-chunk, dg = d-group) ----
  const int c = lane >> 4, dg = lane & 15, d0 = dg << 2;
  const int tbase = c * 13;
  float4 sp4 = make_float4(0, 0, 0, 0), u14 = make_float4(0, 0, 0, 0);
#pragma unroll
  for (int i = 0; i < 13; ++i) {
    if (c < 3 || i < 11) {
      const int t = tbase + i;
      float wt = wv[w][t];
      ushort4 u = *(const ushort4*)&itemsB[w][t][d0];
      float i0 = bf2f(u.x), i1 = bf2f(u.y), i2 = bf2f(u.z), i3 = bf2f(u.w);
      sp4.x += wt * i0; sp4.y += wt * i1;
      sp4.z += wt * i2; sp4.w += wt * i3;
      float wm = ((mask >> t) & 1ull) ? wt : 0.0f;
      u14.x += wm * i0; u14.y += wm * i1;
      u14.z += wm * i2; u14.w += wm * i3;
    }
  }
#pragma unroll
  for (int mm = 16; mm <= 32; mm <<= 1) {
    sp4.x += __shfl_xor(sp4.x, mm, 64); sp4.y += __shfl_xor(sp4.y, mm, 64);
    sp4.z += __shfl_xor(sp4.z, mm, 64); sp4.w += __shfl_xor(sp4.w, mm, 64);
    u14.x += __shfl_xor(u14.x, mm, 64); u14.y += __shfl_xor(u14.y, mm, 64);
    u14.z += __shfl_xor(u14.z, mm, 64); u14.w += __shfl_xor(u14.w, mm, 64);
  }

  float4 al = *(const float4*)&prelu_alpha[d0];
  float4 sp;
  sp.x = sp4.x > 0.0f ? sp4.x : al.x * sp4.x;
  sp.y = sp4.y > 0.0f ? sp4.y : al.y * sp4.y;
  sp.z = sp4.z > 0.0f ? sp4.z : al.z * sp4.z;
  sp.w = sp4.w > 0.0f ? sp4.w : al.w * sp4.w;
  int tgt = target_id[b];
  float4 tv = *(const float4*)&item_table[(size_t)tgt * Dd + d0];
  float op = sp.x * tv.x + sp.y * tv.y + sp.z * tv.z + sp.w * tv.w;
  int result = __shfl(idreg, kl - 1, 64);
  float4 tw = *(const float4*)&item_table[(size_t)result * Dd + d0];
  float tp = u14.x * tw.x + u14.y * tw.y + u14.z * tw.z + u14.w * tw.w;
#pragma unroll
  for (int mm = 1; mm <= 8; mm <<= 1) {
    op += __shfl_xor(op, mm, 64);
    tp += __shfl_xor(tp, mm, 64);
  }
  if (lane == 0) out_vec[b] = op;
  float tl = tp + zero_bias[result] - logq_f(result);
  if (lane < 16) *(float4*)&ut1_lds[w][d0] = u14;

  // ---- phase 4: lane = s -> sampled logits + loss ----
  int sid = sampled_ids[lane];
  const ushort4* srow = (const ushort4*)(ws + WS_SAMP + lane * (Dd * 2));
  const float4* up = (const float4*)&ut1_lds[w][0];
  float acc = 0.0f;
#pragma unroll
  for (int q = 0; q < 16; ++q) {
    ushort4 u = srow[q];
    float4 uv = up[q];  // uniform -> broadcast
    acc += bf2f(u.x) * uv.x + bf2f(u.y) * uv.y + bf2f(u.z) * uv.z +
           bf2f(u.w) * uv.w;
  }
  float sl = acc + zero_bias[sid] - logq_f(sid);
  if (sid == result) sl -= 1e9f;
  float mx = fmaxf(tl, wmax(sl));
  float se = wsum(expf(sl - mx)) + expf(tl - mx);
  float loss_b = (mx + logf(se)) - tl;
  if (lane == 0) red[w] = (long long)rintf(loss_b * 16777216.0f);

  __syncthreads();
  if (tid == 0) {
    long long tot = red[0] + red[1] + red[2] + red[3];
    unsigned long long* slot =
        (unsigned long long*)(ws + WS_SLOTS) + (blockIdx.x & 31) * 8;
    __hip_atomic_fetch_add(slot, (unsigned long long)tot, __ATOMIC_RELAXED,
                           __HIP_MEMORY_SCOPE_AGENT);
    unsigned int* ticket = (unsigned int*)(ws + WS_TICKET);
    unsigned int t = __hip_atomic_fetch_add(ticket, 1u, __ATOMIC_ACQ_REL,
                                            __HIP_MEMORY_SCOPE_AGENT);
    if (t == gridDim.x - 1) {
      long long tot2 = 0;
#pragma unroll
      for (int i = 0; i < 32; ++i)
        tot2 += (long long)__hip_atomic_load(
            (unsigned long long*)(ws + WS_SLOTS) + i * 8, __ATOMIC_RELAXED,
            __HIP_MEMORY_SCOPE_AGENT);
      out_vec[Bb] = (float)((double)tot2 * (1.0 / (16777216.0 * 4096.0)));
    }
  }
}

extern "C" void kernel_launch(void* const* d_in, const int* in_sizes, int n_in,
                              void* d_out, int out_size, void* d_ws, size_t ws_size,
                              hipStream_t stream) {
  const float* item_table  = (const float*)d_in[0];
  const float* pos_table   = (const float*)d_in[1];
  const float* att_W       = (const float*)d_in[2];
  const float* att_b       = (const float*)d_in[3];
  const float* prelu_alpha = (const float*)d_in[4];
  const float* zero_bias   = (const float*)d_in[5];
  const int* items_id      = (const int*)d_in[6];
  const int* position_id   = (const int*)d_in[7];
  const int* target_id     = (const int*)d_in[8];
  const int* keys_length   = (const int*)d_in[9];
  const int* sampled_ids   = (const int*)d_in[10];

  float* out = (float*)d_out;
  unsigned char* ws = (unsigned char*)d_ws;

  pre_kernel<<<5, 256, 0, stream>>>(item_table, pos_table, att_W, sampled_ids, ws);
  u2i_kernel<<<Bb / 4, 256, 0, stream>>>(
      item_table, att_W, att_b, prelu_alpha, zero_bias,
      items_id, position_id, target_id, keys_length, sampled_ids, ws, out);
}

// Round 4
// 27.538 us; speedup vs baseline: 1.5522x; 1.5522x over previous
//
#include <hip/hip_runtime.h>
#include <hip/hip_bf16.h>
#include <math.h>

#define Tt 50
#define Dd 64
#define Bb 4096
#define Ss 64
#define ROWP 68  // padded LDS row (ushorts); 136 B rows, 8B-aligned

__device__ __forceinline__ float wsum(float v) {
#pragma unroll
  for (int m = 32; m >= 1; m >>= 1) v += __shfl_xor(v, m, 64);
  return v;
}
__device__ __forceinline__ float wmax(float v) {
#pragma unroll
  for (int m = 32; m >= 1; m >>= 1) v = fmaxf(v, __shfl_xor(v, m, 64));
  return v;
}
__device__ __forceinline__ float bf2f(unsigned short u) {
  return __uint_as_float(((unsigned)u) << 16);
}
__device__ __forceinline__ unsigned short f2bf(float f) {
  __hip_bfloat16 h = __float2bfloat16(f);  // RNE
  return __builtin_bit_cast(unsigned short, h);
}
// log(q), cancellation-free: log(id+2)-log(id+1) == log1p(1/(id+1))
__device__ __forceinline__ float logq_f(int id) {
  float idf = (float)id;
  float r = log1pf(1.0f / (idf + 1.0f));
  return logf(r * (1.0f / 12.2060776f));  // ln(200001)
}

__global__ __launch_bounds__(256, 4) void u2i_kernel(
    const float* __restrict__ item_table,
    const float* __restrict__ att_W,
    const float* __restrict__ att_b,
    const float* __restrict__ prelu_alpha,
    const float* __restrict__ zero_bias,
    const int* __restrict__ items_id,
    const int* __restrict__ position_id,
    const int* __restrict__ target_id,
    const int* __restrict__ keys_length,
    const int* __restrict__ sampled_ids,
    float* __restrict__ out_vec,   // [B]
    float* __restrict__ loss_ws)   // [B]
{
  __shared__ unsigned short itemsB[4][Tt][ROWP];  // 27200 B (bf16, per-wave)
  __shared__ unsigned short sampB[Ss][ROWP];      //  8704 B (bf16, block-shared)
  __shared__ float poss[52];                      //   208 B
  __shared__ float wv[4][Dd];
  __shared__ float ut1_lds[4][Dd];

  const int tid = threadIdx.x;
  const int lane = tid & 63;
  const int w = tid >> 6;
  const int b = (blockIdx.x << 2) | w;

  int idreg = 0, pidreg = 0;
  if (lane < Tt) {
    idreg = items_id[b * Tt + lane];
    pidreg = position_id[b * Tt + lane];
  }
  const int kl = keys_length[b];

  const int sub = lane >> 4;        // 0..3
  const int dg = lane & 15;         // 0..15
  const int d0 = dg << 2;

  // ---- stage this wave's 50 item rows -> LDS bf16: 13 x float4 (4 rows/instr)
#pragma unroll
  for (int c = 0; c < 13; ++c) {
    int t = 4 * c + sub;
    bool v = (t < Tt);
    int iid = __shfl(idreg, v ? t : 0, 64);
    if (v) {
      float4 x = *(const float4*)&item_table[(size_t)iid * Dd + d0];
      ushort4 o;
      o.x = f2bf(x.x); o.y = f2bf(x.y); o.z = f2bf(x.z); o.w = f2bf(x.w);
      *(ushort4*)&itemsB[w][t][d0] = o;
    }
  }

  // ---- stage sampled table -> LDS bf16 (block-cooperative, 4 passes) ----
#pragma unroll
  for (int k = 0; k < 4; ++k) {
    int s = (tid >> 4) + 16 * k;
    int sd0 = (tid & 15) << 2;
    float4 x = *(const float4*)&item_table[(size_t)sampled_ids[s] * Dd + sd0];
    ushort4 o;
    o.x = f2bf(x.x); o.y = f2bf(x.y); o.z = f2bf(x.z); o.w = f2bf(x.w);
    *(ushort4*)&sampB[s][sd0] = o;
  }

  // ---- pos_score[p] = dot(pos_table-row p, Wp): wave w owns p in [13w,13w+13)
  {
    float4 wp4 = *(const float4*)&att_W[Dd + d0];
#pragma unroll
    for (int j = 0; j < 4; ++j) {
      int rel = 4 * j + sub;
      int p = 13 * w + rel;
      bool v = (rel < 13) && (p < Tt);
      float part = 0.0f;
      if (v) {
        // reuse att_W pointer trick: pos_table passed via att_W? no — see arg below
      }
      (void)part; (void)v; (void)p;
    }
  }
  // (pos staging moved below — needs pos_table pointer; see pos_stage())
  // placeholder removed in actual code path:

  __syncthreads();  // dummy never reached -- real code continues below
}

// NOTE: restructured into a single kernel below (the above stub is unused).

__global__ __launch_bounds__(256, 4) void u2i_main(
    const float* __restrict__ item_table,
    const float* __restrict__ pos_table,
    const float* __restrict__ att_W,
    const float* __restrict__ att_b,
    const float* __restrict__ prelu_alpha,
    const float* __restrict__ zero_bias,
    const int* __restrict__ items_id,
    const int* __restrict__ position_id,
    const int* __restrict__ target_id,
    const int* __restrict__ keys_length,
    const int* __restrict__ sampled_ids,
    float* __restrict__ out_vec,   // [B]
    float* __restrict__ loss_ws)   // [B]
{
  __shared__ unsigned short itemsB[4][Tt][ROWP];  // 27200 B
  __shared__ unsigned short sampB[Ss][ROWP];      //  8704 B
  __shared__ float poss[52];
  __shared__ float wv[4][Dd];
  __shared__ float ut1_lds[4][Dd];

  const int tid = threadIdx.x;
  const int lane = tid & 63;
  const int w = tid >> 6;
  const int b = (blockIdx.x << 2) | w;

  int idreg = 0, pidreg = 0;
  if (lane < Tt) {
    idreg = items_id[b * Tt + lane];
    pidreg = position_id[b * Tt + lane];
  }
  const int kl = keys_length[b];

  const int sub = lane >> 4;  // 0..3
  const int dg = lane & 15;   // 0..15
  const int d0g = dg << 2;

  // ---- stage 50 item rows (bf16), 4 rows per float4 instruction ----
#pragma unroll
  for (int c = 0; c < 13; ++c) {
    int t = 4 * c + sub;
    bool v = (t < Tt);
    int iid = __shfl(idreg, v ? t : 0, 64);
    if (v) {
      float4 x = *(const float4*)&item_table[(size_t)iid * Dd + d0g];
      ushort4 o;
      o.x = f2bf(x.x); o.y = f2bf(x.y); o.z = f2bf(x.z); o.w = f2bf(x.w);
      *(ushort4*)&itemsB[w][t][d0g] = o;
    }
  }

  // ---- stage sampled table (block-cooperative, 4 passes) ----
#pragma unroll
  for (int k = 0; k < 4; ++k) {
    int s = (tid >> 4) + 16 * k;
    float4 x = *(const float4*)&item_table[(size_t)sampled_ids[s] * Dd + d0g];
    ushort4 o;
    o.x = f2bf(x.x); o.y = f2bf(x.y); o.z = f2bf(x.z); o.w = f2bf(x.w);
    *(ushort4*)&sampB[s][d0g] = o;
  }

  // ---- pos_score: wave w owns p in [13w, 13w+13), 4 passes, 16-lane reduce
  {
    float4 wp4 = *(const float4*)&att_W[Dd + d0g];
#pragma unroll
    for (int j = 0; j < 4; ++j) {
      int rel = 4 * j + sub;
      int p = 13 * w + rel;
      bool v = (rel < 13) && (p < Tt);
      float part = 0.0f;
      if (v) {
        float4 x = *(const float4*)&pos_table[p * Dd + d0g];
        part = x.x * wp4.x + x.y * wp4.y + x.z * wp4.z + x.w * wp4.w;
      }
#pragma unroll
      for (int mm = 1; mm <= 8; mm <<= 1) part += __shfl_xor(part, mm, 64);
      if (v && dg == 0) poss[p] = part;
    }
  }
  __syncthreads();

  // ---- phase 2: lane = t -> score, softmax ----
  const int trow = (lane < Tt) ? lane : (Tt - 1);
  const ushort4* rowp = (const ushort4*)&itemsB[w][trow][0];
  float a0 = 0, a1 = 0, a2 = 0, a3 = 0;
#pragma unroll
  for (int q = 0; q < 16; ++q) {
    ushort4 u = rowp[q];
    a0 += bf2f(u.x) * att_W[4 * q + 0];
    a1 += bf2f(u.y) * att_W[4 * q + 1];
    a2 += bf2f(u.z) * att_W[4 * q + 2];
    a3 += bf2f(u.w) * att_W[4 * q + 3];
  }
  float sc = tanhf((a0 + a1) + (a2 + a3) + poss[pidreg] + att_b[0]);
  float scv = (lane < kl) ? sc : -INFINITY;
  float m = wmax(scv);
  float e = (lane < kl) ? expf(sc - m) : 0.0f;
  float denom = wsum(e);
  wv[w][lane] = e / denom;
  unsigned long long mask = __ballot(lane < Tt - 1 && idreg != 0);

  // ---- phase 3: lane = (c = t-chunk, dg) -> pooling, output, true logit ----
  const int tbase = (lane >> 4) * 13;
  float4 sp4 = make_float4(0, 0, 0, 0), u14 = make_float4(0, 0, 0, 0);
#pragma unroll
  for (int i = 0; i < 13; ++i) {
    if ((lane >> 4) < 3 || i < 11) {
      const int t = tbase + i;
      float wt = wv[w][t];
      ushort4 u = *(const ushort4*)&itemsB[w][t][d0g];
      float i0 = bf2f(u.x), i1 = bf2f(u.y), i2 = bf2f(u.z), i3 = bf2f(u.w);
      sp4.x += wt * i0; sp4.y += wt * i1;
      sp4.z += wt * i2; sp4.w += wt * i3;
      float wm = ((mask >> t) & 1ull) ? wt : 0.0f;
      u14.x += wm * i0; u14.y += wm * i1;
      u14.z += wm * i2; u14.w += wm * i3;
    }
  }
#pragma unroll
  for (int mm = 16; mm <= 32; mm <<= 1) {
    sp4.x += __shfl_xor(sp4.x, mm, 64); sp4.y += __shfl_xor(sp4.y, mm, 64);
    sp4.z += __shfl_xor(sp4.z, mm, 64); sp4.w += __shfl_xor(sp4.w, mm, 64);
    u14.x += __shfl_xor(u14.x, mm, 64); u14.y += __shfl_xor(u14.y, mm, 64);
    u14.z += __shfl_xor(u14.z, mm, 64); u14.w += __shfl_xor(u14.w, mm, 64);
  }

  float4 al = *(const float4*)&prelu_alpha[d0g];
  float4 sp;
  sp.x = sp4.x > 0.0f ? sp4.x : al.x * sp4.x;
  sp.y = sp4.y > 0.0f ? sp4.y : al.y * sp4.y;
  sp.z = sp4.z > 0.0f ? sp4.z : al.z * sp4.z;
  sp.w = sp4.w > 0.0f ? sp4.w : al.w * sp4.w;
  int tgt = target_id[b];
  float4 tv = *(const float4*)&item_table[(size_t)tgt * Dd + d0g];
  float op = sp.x * tv.x + sp.y * tv.y + sp.z * tv.z + sp.w * tv.w;
  int result = __shfl(idreg, kl - 1, 64);
  float4 tw = *(const float4*)&item_table[(size_t)result * Dd + d0g];
  float tp = u14.x * tw.x + u14.y * tw.y + u14.z * tw.z + u14.w * tw.w;
#pragma unroll
  for (int mm = 1; mm <= 8; mm <<= 1) {
    op += __shfl_xor(op, mm, 64);
    tp += __shfl_xor(tp, mm, 64);
  }
  if (lane == 0) out_vec[b] = op;
  float tl = tp + zero_bias[result] - logq_f(result);
  if (lane < 16) *(float4*)&ut1_lds[w][d0g] = u14;

  // ---- phase 4: lane = s -> sampled logits + loss ----
  int sid = sampled_ids[lane];
  const ushort4* srow = (const ushort4*)&sampB[lane][0];
  const float4* up = (const float4*)&ut1_lds[w][0];
  float acc = 0.0f;
#pragma unroll
  for (int q = 0; q < 16; ++q) {
    ushort4 u = srow[q];
    float4 uv = up[q];  // uniform -> broadcast
    acc += bf2f(u.x) * uv.x + bf2f(u.y) * uv.y + bf2f(u.z) * uv.z +
           bf2f(u.w) * uv.w;
  }
  float sl = acc + zero_bias[sid] - logq_f(sid);
  if (sid == result) sl -= 1e9f;
  float mx = fmaxf(tl, wmax(sl));
  float se = wsum(expf(sl - mx)) + expf(tl - mx);
  if (lane == 0) loss_ws[b] = (mx + logf(se)) - tl;
}

__global__ __launch_bounds__(256) void loss_reduce_kernel(
    const float* __restrict__ ws, float* __restrict__ out_loss) {
  __shared__ float red[4];
  float acc = 0.0f;
  for (int i = threadIdx.x; i < Bb; i += 256) acc += ws[i];
  acc = wsum(acc);
  if ((threadIdx.x & 63) == 0) red[threadIdx.x >> 6] = acc;
  __syncthreads();
  if (threadIdx.x == 0)
    out_loss[0] = (red[0] + red[1] + red[2] + red[3]) * (1.0f / (float)Bb);
}

extern "C" void kernel_launch(void* const* d_in, const int* in_sizes, int n_in,
                              void* d_out, int out_size, void* d_ws, size_t ws_size,
                              hipStream_t stream) {
  const float* item_table  = (const float*)d_in[0];
  const float* pos_table   = (const float*)d_in[1];
  const float* att_W       = (const float*)d_in[2];
  const float* att_b       = (const float*)d_in[3];
  const float* prelu_alpha = (const float*)d_in[4];
  const float* zero_bias   = (const float*)d_in[5];
  const int* items_id      = (const int*)d_in[6];
  const int* position_id   = (const int*)d_in[7];
  const int* target_id     = (const int*)d_in[8];
  const int* keys_length   = (const int*)d_in[9];
  const int* sampled_ids   = (const int*)d_in[10];

  float* out = (float*)d_out;     // [0..4095]=output, [4096]=loss
  float* loss_ws = (float*)d_ws;  // B floats

  u2i_main<<<Bb / 4, 256, 0, stream>>>(
      item_table, pos_table, att_W, att_b, prelu_alpha, zero_bias,
      items_id, position_id, target_id, keys_length, sampled_ids,
      out, loss_ws);
  loss_reduce_kernel<<<1, 256, 0, stream>>>(loss_ws, out + Bb);
}